// Round 1
// baseline (495.048 us; speedup 1.0000x reference)
//
#include <hip/hip_runtime.h>

// Problem constants (match reference)
constexpr int K_CODES = 1024;
constexpr int D_DIM   = 512;
constexpr float DECAY = 0.99f;
constexpr float OMD   = 0.01f;   // (1 - DECAY) in fp32

// GEMM tiling for argmin
constexpr int BM = 64;
constexpr int BN = 64;
constexpr int BK = 16;
constexpr int COLS_PER_BLOCK = 512;   // K split across gridDim.y = 2

// ---------------------------------------------------------------------------
// zero-fill scratch (counts + dw) — harness poisons ws with 0xAA, we must init
__global__ __launch_bounds__(256) void zero_kernel(float4* __restrict__ p, int n4) {
    int i = blockIdx.x * 256 + threadIdx.x;
    if (i < n4) p[i] = make_float4(0.f, 0.f, 0.f, 0.f);
}

// ---------------------------------------------------------------------------
// cb_sqr[k] = sum_d codebook[k][d]^2  — one wave per row
__global__ __launch_bounds__(64) void cbsqr_kernel(const float* __restrict__ cb,
                                                   float* __restrict__ out) {
    int k = blockIdx.x;
    int lane = threadIdx.x;
    float s = 0.f;
    for (int d = lane; d < D_DIM; d += 64) {
        float v = cb[(size_t)k * D_DIM + d];
        s += v * v;
    }
    #pragma unroll
    for (int off = 32; off > 0; off >>= 1) s += __shfl_down(s, off);
    if (lane == 0) out[k] = s;
}

// ---------------------------------------------------------------------------
// Fused GEMM + running argmin over a K-half.
// dist(r,c) = cb_sqr[c] - 2 * dot(x_r, c_c)   (row-constant ||x||^2 dropped)
__global__ __launch_bounds__(256)
void argmin_part(const float* __restrict__ A,      // [N, D] z_e_x flat
                 const float* __restrict__ B,      // [K, D] codebook
                 const float* __restrict__ cbsqr,  // [K]
                 float* __restrict__ pval,         // [N, 2]
                 int*   __restrict__ pidx) {       // [N, 2]
    __shared__ float As[BK][BM];
    __shared__ float Bs[BK][BN];
    __shared__ float rv[BM][16];
    __shared__ int   ri[BM][16];

    const int row0  = blockIdx.x * BM;
    const int cbase = blockIdx.y * COLS_PER_BLOCK;
    const int tid = threadIdx.x;
    const int tx = tid & 15;        // 16 col-threads
    const int ty = tid >> 4;        // 16 row-threads
    const int lr = tid >> 2;        // staging: row 0..63
    const int ld = (tid & 3) * 4;   // staging: d offset 0/4/8/12

    float minv[4];
    int   mini[4];
    #pragma unroll
    for (int i = 0; i < 4; ++i) { minv[i] = 3.4e38f; mini[i] = 0; }

    for (int c0 = cbase; c0 < cbase + COLS_PER_BLOCK; c0 += BN) {
        float acc[4][4] = {};
        for (int d0 = 0; d0 < D_DIM; d0 += BK) {
            float4 a = *reinterpret_cast<const float4*>(&A[(size_t)(row0 + lr) * D_DIM + d0 + ld]);
            float4 b = *reinterpret_cast<const float4*>(&B[(size_t)(c0 + lr) * D_DIM + d0 + ld]);
            As[ld + 0][lr] = a.x; As[ld + 1][lr] = a.y;
            As[ld + 2][lr] = a.z; As[ld + 3][lr] = a.w;
            Bs[ld + 0][lr] = b.x; Bs[ld + 1][lr] = b.y;
            Bs[ld + 2][lr] = b.z; Bs[ld + 3][lr] = b.w;
            __syncthreads();
            #pragma unroll
            for (int dd = 0; dd < BK; ++dd) {
                float4 av = *reinterpret_cast<const float4*>(&As[dd][ty * 4]);
                float4 bv = *reinterpret_cast<const float4*>(&Bs[dd][tx * 4]);
                float aa[4] = {av.x, av.y, av.z, av.w};
                float bb[4] = {bv.x, bv.y, bv.z, bv.w};
                #pragma unroll
                for (int i = 0; i < 4; ++i)
                    #pragma unroll
                    for (int j = 0; j < 4; ++j)
                        acc[i][j] += aa[i] * bb[j];
            }
            __syncthreads();
        }
        // fold this col-tile into the running argmin (ascending c => strict <
        // keeps the FIRST minimum, matching jnp.argmin tie-break)
        #pragma unroll
        for (int j = 0; j < 4; ++j) {
            int c = c0 + tx * 4 + j;
            float cs = cbsqr[c];
            #pragma unroll
            for (int i = 0; i < 4; ++i) {
                float dist = cs - 2.0f * acc[i][j];
                if (dist < minv[i]) { minv[i] = dist; mini[i] = c; }
            }
        }
        __syncthreads();   // before re-staging As/Bs next iteration
    }

    // cross-thread reduce: 16 tx-threads per row
    #pragma unroll
    for (int i = 0; i < 4; ++i) {
        rv[ty * 4 + i][tx] = minv[i];
        ri[ty * 4 + i][tx] = mini[i];
    }
    __syncthreads();
    if (tid < BM) {
        float bv = rv[tid][0];
        int   bi = ri[tid][0];
        #pragma unroll
        for (int t = 1; t < 16; ++t) {
            float v = rv[tid][t];
            int  ii = ri[tid][t];
            if (v < bv || (v == bv && ii < bi)) { bv = v; bi = ii; }
        }
        pval[(size_t)(row0 + tid) * 2 + blockIdx.y] = bv;
        pidx[(size_t)(row0 + tid) * 2 + blockIdx.y] = bi;
    }
}

// ---------------------------------------------------------------------------
// combine the two K-halves, emit final index, accumulate counts
__global__ __launch_bounds__(256)
void combine_kernel(const float* __restrict__ pval, const int* __restrict__ pidx,
                    int* __restrict__ indices, float* __restrict__ counts, int N) {
    int r = blockIdx.x * 256 + threadIdx.x;
    if (r >= N) return;
    float v0 = pval[(size_t)r * 2 + 0], v1 = pval[(size_t)r * 2 + 1];
    int   i0 = pidx[(size_t)r * 2 + 0], i1 = pidx[(size_t)r * 2 + 1];
    // half 0 always has the smaller index -> on tie keep i0 (first occurrence)
    int idx = (v1 < v0) ? i1 : i0;
    indices[r] = idx;
    atomicAdd(&counts[idx], 1.0f);
}

// ---------------------------------------------------------------------------
// dw[k][d] += flat[r][d] for k = indices[r]   (float atomics, ~1e-6 rounding)
__global__ __launch_bounds__(256)
void dw_kernel(const float* __restrict__ flat, const int* __restrict__ indices,
               float* __restrict__ dw) {
    int gid = blockIdx.x * 256 + threadIdx.x;   // N*D/4 threads
    int r = gid >> 7;                // 128 float4 threads per row
    int d = (gid & 127) * 4;
    int k = indices[r];
    float4 v = *reinterpret_cast<const float4*>(&flat[(size_t)r * D_DIM + d]);
    float* p = &dw[(size_t)k * D_DIM + d];
    atomicAdd(p + 0, v.x);
    atomicAdd(p + 1, v.y);
    atomicAdd(p + 2, v.z);
    atomicAdd(p + 3, v.w);
}

// ---------------------------------------------------------------------------
// EMA update + new embedding
__global__ __launch_bounds__(256)
void finalize_kernel(const float* __restrict__ ema_count, const float* __restrict__ ema_w,
                     const float* __restrict__ counts, const float* __restrict__ dw,
                     float* __restrict__ new_emb, float* __restrict__ new_count,
                     float* __restrict__ new_ema_w) {
    int gid = blockIdx.x * 256 + threadIdx.x;   // K*D/4 threads
    int k = gid >> 7;
    int d = (gid & 127) * 4;
    float nc = DECAY * ema_count[k] + OMD * counts[k];
    size_t off = (size_t)k * D_DIM + d;
    float4 w  = *reinterpret_cast<const float4*>(&ema_w[off]);
    float4 dv = *reinterpret_cast<const float4*>(&dw[off]);
    float4 nw;
    nw.x = DECAY * w.x + OMD * dv.x;
    nw.y = DECAY * w.y + OMD * dv.y;
    nw.z = DECAY * w.z + OMD * dv.z;
    nw.w = DECAY * w.w + OMD * dv.w;
    *reinterpret_cast<float4*>(&new_ema_w[off]) = nw;
    float inv = 1.0f / nc;
    float4 ne;
    ne.x = nw.x * inv; ne.y = nw.y * inv; ne.z = nw.z * inv; ne.w = nw.w * inv;
    *reinterpret_cast<float4*>(&new_emb[off]) = ne;
    if ((gid & 127) == 0) new_count[k] = nc;
}

// ---------------------------------------------------------------------------
// z_q_x = codebook[idx], z_q_x_bar = new_embedding[idx]
__global__ __launch_bounds__(256)
void gather_kernel(const float* __restrict__ codebook, const float* __restrict__ new_emb,
                   const int* __restrict__ indices,
                   float* __restrict__ zq, float* __restrict__ zqb) {
    int gid = blockIdx.x * 256 + threadIdx.x;   // N*D/4 threads
    int r = gid >> 7;
    int d = (gid & 127) * 4;
    int k = indices[r];
    size_t src = (size_t)k * D_DIM + d;
    size_t dst = (size_t)r * D_DIM + d;
    *reinterpret_cast<float4*>(&zq[dst])  = *reinterpret_cast<const float4*>(&codebook[src]);
    *reinterpret_cast<float4*>(&zqb[dst]) = *reinterpret_cast<const float4*>(&new_emb[src]);
}

// ---------------------------------------------------------------------------
extern "C" void kernel_launch(void* const* d_in, const int* in_sizes, int n_in,
                              void* d_out, int out_size, void* d_ws, size_t ws_size,
                              hipStream_t stream) {
    const float* z_e_x     = (const float*)d_in[0];
    const float* codebook  = (const float*)d_in[1];
    const float* ema_count = (const float*)d_in[2];
    const float* ema_w     = (const float*)d_in[3];

    const int N = in_sizes[0] / D_DIM;   // 16384

    float* out = (float*)d_out;
    float* z_q_x     = out;
    float* z_q_x_bar = z_q_x + (size_t)N * D_DIM;
    float* new_emb   = z_q_x_bar + (size_t)N * D_DIM;
    float* new_count = new_emb + (size_t)K_CODES * D_DIM;
    float* new_ema_w = new_count + K_CODES;

    // workspace layout: indices | cbsqr | pval | pidx | counts | dw
    char* ws = (char*)d_ws;
    int*   indices = (int*)ws;                                   // N ints
    float* cbsqr   = (float*)(ws + (size_t)N * 4);               // K
    float* pval    = cbsqr + K_CODES;                            // N*2
    int*   pidx    = (int*)(pval + (size_t)N * 2);               // N*2
    float* counts  = (float*)(pidx + (size_t)N * 2);             // K
    float* dw      = counts + K_CODES;                           // K*D
    // counts+dw are contiguous: zero them together
    const int zero_f = K_CODES + K_CODES * D_DIM;                // 525312 floats
    zero_kernel<<<(zero_f / 4 + 255) / 256, 256, 0, stream>>>((float4*)counts, zero_f / 4);

    cbsqr_kernel<<<K_CODES, 64, 0, stream>>>(codebook, cbsqr);

    dim3 g_argmin(N / BM, K_CODES / COLS_PER_BLOCK);   // (256, 2)
    argmin_part<<<g_argmin, 256, 0, stream>>>(z_e_x, codebook, cbsqr, pval, pidx);

    combine_kernel<<<(N + 255) / 256, 256, 0, stream>>>(pval, pidx, indices, counts, N);

    dw_kernel<<<(N * (D_DIM / 4)) / 256, 256, 0, stream>>>(z_e_x, indices, dw);

    finalize_kernel<<<(K_CODES * (D_DIM / 4)) / 256, 256, 0, stream>>>(
        ema_count, ema_w, counts, dw, new_emb, new_count, new_ema_w);

    gather_kernel<<<(N * (D_DIM / 4)) / 256, 256, 0, stream>>>(
        codebook, new_emb, indices, z_q_x, z_q_x_bar);
}

// Round 2
// 393.897 us; speedup vs baseline: 1.2568x; 1.2568x over previous
//
#include <hip/hip_runtime.h>

// Problem constants (match reference)
constexpr int K_CODES = 1024;
constexpr int D_DIM   = 512;
constexpr float DECAY = 0.99f;
constexpr float OMD   = 0.01f;   // (1 - DECAY) in fp32

// GEMM tiling for argmin
constexpr int BM = 128;          // rows per block
constexpr int BN = 128;          // cols per block (also the K-split width)
constexpr int BK = 16;
constexpr int NPART = K_CODES / BN;   // 8 partials per row

// ---------------------------------------------------------------------------
// zero-fill scratch (counts + dw) — harness poisons ws with 0xAA, we must init
__global__ __launch_bounds__(256) void zero_kernel(float4* __restrict__ p, int n4) {
    int i = blockIdx.x * 256 + threadIdx.x;
    if (i < n4) p[i] = make_float4(0.f, 0.f, 0.f, 0.f);
}

// ---------------------------------------------------------------------------
// cb_sqr[k] = sum_d codebook[k][d]^2  — one wave per row
__global__ __launch_bounds__(64) void cbsqr_kernel(const float* __restrict__ cb,
                                                   float* __restrict__ out) {
    int k = blockIdx.x;
    int lane = threadIdx.x;
    float s = 0.f;
    for (int d = lane; d < D_DIM; d += 64) {
        float v = cb[(size_t)k * D_DIM + d];
        s += v * v;
    }
    #pragma unroll
    for (int off = 32; off > 0; off >>= 1) s += __shfl_down(s, off);
    if (lane == 0) out[k] = s;
}

// ---------------------------------------------------------------------------
// Fused GEMM + running argmin over one 128-col K-slice.
// dist(r,c) = cb_sqr[c] - 2 * dot(x_r, c_c)   (row-constant ||x||^2 dropped)
// 256 thr, 128x128 tile, 8x8 micro-tile as 2x2 blocks of 4x4 so every LDS
// fragment read is a b128 at 16B lane-stride (2-way conflict = free).
__global__ __launch_bounds__(256, 4)
void argmin_part(const float* __restrict__ A,      // [N, D] z_e_x flat
                 const float* __restrict__ B,      // [K, D] codebook
                 const float* __restrict__ cbsqr,  // [K]
                 float* __restrict__ pval,         // [N, NPART]
                 int*   __restrict__ pidx) {       // [N, NPART]
    __shared__ float As[BK][BM + 4];   // +4 pad: stride 132 ≡ 4 mod 32 banks,
    __shared__ float Bs[BK][BN + 4];   // keeps 16B alignment for b128 reads
    __shared__ float rv[BM][17];
    __shared__ int   ri[BM][17];

    const int row0  = blockIdx.x * BM;
    const int cbase = blockIdx.y * BN;
    const int tid = threadIdx.x;
    const int tx = tid & 15;        // 16 col-threads
    const int ty = tid >> 4;        // 16 row-threads
    const int lr = tid >> 2;        // staging: row 0..63 (+64 second half)
    const int ld = (tid & 3) * 4;   // staging: d offset 0/4/8/12

    float acc[2][2][4][4] = {};     // [rowhalf][colhalf][i][j]

    for (int d0 = 0; d0 < D_DIM; d0 += BK) {
        #pragma unroll
        for (int h = 0; h < 2; ++h) {
            int r = lr + h * 64;
            float4 a = *reinterpret_cast<const float4*>(&A[(size_t)(row0 + r) * D_DIM + d0 + ld]);
            float4 b = *reinterpret_cast<const float4*>(&B[(size_t)(cbase + r) * D_DIM + d0 + ld]);
            As[ld + 0][r] = a.x; As[ld + 1][r] = a.y;
            As[ld + 2][r] = a.z; As[ld + 3][r] = a.w;
            Bs[ld + 0][r] = b.x; Bs[ld + 1][r] = b.y;
            Bs[ld + 2][r] = b.z; Bs[ld + 3][r] = b.w;
        }
        __syncthreads();
        #pragma unroll
        for (int dd = 0; dd < BK; ++dd) {
            float4 a0 = *reinterpret_cast<const float4*>(&As[dd][ty * 4]);
            float4 a1 = *reinterpret_cast<const float4*>(&As[dd][64 + ty * 4]);
            float4 b0 = *reinterpret_cast<const float4*>(&Bs[dd][tx * 4]);
            float4 b1 = *reinterpret_cast<const float4*>(&Bs[dd][64 + tx * 4]);
            float av[2][4] = {{a0.x, a0.y, a0.z, a0.w}, {a1.x, a1.y, a1.z, a1.w}};
            float bw[2][4] = {{b0.x, b0.y, b0.z, b0.w}, {b1.x, b1.y, b1.z, b1.w}};
            #pragma unroll
            for (int h = 0; h < 2; ++h)
                #pragma unroll
                for (int b = 0; b < 2; ++b)
                    #pragma unroll
                    for (int i = 0; i < 4; ++i)
                        #pragma unroll
                        for (int j = 0; j < 4; ++j)
                            acc[h][b][i][j] += av[h][i] * bw[b][j];
        }
        __syncthreads();
    }

    // per-thread argmin over its 8 cols x 8 rows; ascending c + strict '<'
    // keeps the FIRST minimum (matches jnp.argmin tie-break)
    float minv[2][4];
    int   mini[2][4];
    #pragma unroll
    for (int h = 0; h < 2; ++h)
        #pragma unroll
        for (int i = 0; i < 4; ++i) { minv[h][i] = 3.4e38f; mini[h][i] = 0; }

    #pragma unroll
    for (int b = 0; b < 2; ++b) {
        #pragma unroll
        for (int j = 0; j < 4; ++j) {
            int c = cbase + b * 64 + tx * 4 + j;
            float cs = cbsqr[c];
            #pragma unroll
            for (int h = 0; h < 2; ++h)
                #pragma unroll
                for (int i = 0; i < 4; ++i) {
                    float dist = cs - 2.0f * acc[h][b][i][j];
                    if (dist < minv[h][i]) { minv[h][i] = dist; mini[h][i] = c; }
                }
        }
    }

    // cross-thread reduce: 16 tx-threads per row
    #pragma unroll
    for (int h = 0; h < 2; ++h)
        #pragma unroll
        for (int i = 0; i < 4; ++i) {
            rv[h * 64 + ty * 4 + i][tx] = minv[h][i];
            ri[h * 64 + ty * 4 + i][tx] = mini[h][i];
        }
    __syncthreads();
    if (tid < BM) {
        float bv = rv[tid][0];
        int   bi = ri[tid][0];
        #pragma unroll
        for (int t = 1; t < 16; ++t) {
            float v = rv[tid][t];
            int  ii = ri[tid][t];
            if (v < bv || (v == bv && ii < bi)) { bv = v; bi = ii; }
        }
        pval[(size_t)(row0 + tid) * NPART + blockIdx.y] = bv;
        pidx[(size_t)(row0 + tid) * NPART + blockIdx.y] = bi;
    }
}

// ---------------------------------------------------------------------------
// combine the NPART K-slices, emit final index, accumulate counts
__global__ __launch_bounds__(256)
void combine_kernel(const float* __restrict__ pval, const int* __restrict__ pidx,
                    int* __restrict__ indices, float* __restrict__ counts, int N) {
    int r = blockIdx.x * 256 + threadIdx.x;
    if (r >= N) return;
    float bv = pval[(size_t)r * NPART];
    int   bi = pidx[(size_t)r * NPART];
    #pragma unroll
    for (int p = 1; p < NPART; ++p) {
        float v = pval[(size_t)r * NPART + p];
        int  ii = pidx[(size_t)r * NPART + p];
        // parts are in ascending col-block order: strict '<' keeps first min
        if (v < bv) { bv = v; bi = ii; }
    }
    indices[r] = bi;
    atomicAdd(&counts[bi], 1.0f);
}

// ---------------------------------------------------------------------------
// dw[k][d] += flat[r][d] for k = indices[r]   (float atomics, ~1e-6 rounding)
__global__ __launch_bounds__(256)
void dw_kernel(const float* __restrict__ flat, const int* __restrict__ indices,
               float* __restrict__ dw) {
    int gid = blockIdx.x * 256 + threadIdx.x;   // N*D/4 threads
    int r = gid >> 7;                // 128 float4 threads per row
    int d = (gid & 127) * 4;
    int k = indices[r];
    float4 v = *reinterpret_cast<const float4*>(&flat[(size_t)r * D_DIM + d]);
    float* p = &dw[(size_t)k * D_DIM + d];
    atomicAdd(p + 0, v.x);
    atomicAdd(p + 1, v.y);
    atomicAdd(p + 2, v.z);
    atomicAdd(p + 3, v.w);
}

// ---------------------------------------------------------------------------
// EMA update + new embedding
__global__ __launch_bounds__(256)
void finalize_kernel(const float* __restrict__ ema_count, const float* __restrict__ ema_w,
                     const float* __restrict__ counts, const float* __restrict__ dw,
                     float* __restrict__ new_emb, float* __restrict__ new_count,
                     float* __restrict__ new_ema_w) {
    int gid = blockIdx.x * 256 + threadIdx.x;   // K*D/4 threads
    int k = gid >> 7;
    int d = (gid & 127) * 4;
    float nc = DECAY * ema_count[k] + OMD * counts[k];
    size_t off = (size_t)k * D_DIM + d;
    float4 w  = *reinterpret_cast<const float4*>(&ema_w[off]);
    float4 dv = *reinterpret_cast<const float4*>(&dw[off]);
    float4 nw;
    nw.x = DECAY * w.x + OMD * dv.x;
    nw.y = DECAY * w.y + OMD * dv.y;
    nw.z = DECAY * w.z + OMD * dv.z;
    nw.w = DECAY * w.w + OMD * dv.w;
    *reinterpret_cast<float4*>(&new_ema_w[off]) = nw;
    float inv = 1.0f / nc;
    float4 ne;
    ne.x = nw.x * inv; ne.y = nw.y * inv; ne.z = nw.z * inv; ne.w = nw.w * inv;
    *reinterpret_cast<float4*>(&new_emb[off]) = ne;
    if ((gid & 127) == 0) new_count[k] = nc;
}

// ---------------------------------------------------------------------------
// z_q_x = codebook[idx], z_q_x_bar = new_embedding[idx]
__global__ __launch_bounds__(256)
void gather_kernel(const float* __restrict__ codebook, const float* __restrict__ new_emb,
                   const int* __restrict__ indices,
                   float* __restrict__ zq, float* __restrict__ zqb) {
    int gid = blockIdx.x * 256 + threadIdx.x;   // N*D/4 threads
    int r = gid >> 7;
    int d = (gid & 127) * 4;
    int k = indices[r];
    size_t src = (size_t)k * D_DIM + d;
    size_t dst = (size_t)r * D_DIM + d;
    *reinterpret_cast<float4*>(&zq[dst])  = *reinterpret_cast<const float4*>(&codebook[src]);
    *reinterpret_cast<float4*>(&zqb[dst]) = *reinterpret_cast<const float4*>(&new_emb[src]);
}

// ---------------------------------------------------------------------------
extern "C" void kernel_launch(void* const* d_in, const int* in_sizes, int n_in,
                              void* d_out, int out_size, void* d_ws, size_t ws_size,
                              hipStream_t stream) {
    const float* z_e_x     = (const float*)d_in[0];
    const float* codebook  = (const float*)d_in[1];
    const float* ema_count = (const float*)d_in[2];
    const float* ema_w     = (const float*)d_in[3];

    const int N = in_sizes[0] / D_DIM;   // 16384

    float* out = (float*)d_out;
    float* z_q_x     = out;
    float* z_q_x_bar = z_q_x + (size_t)N * D_DIM;
    float* new_emb   = z_q_x_bar + (size_t)N * D_DIM;
    float* new_count = new_emb + (size_t)K_CODES * D_DIM;
    float* new_ema_w = new_count + K_CODES;

    // workspace layout: indices | cbsqr | pval | pidx | counts | dw
    char* ws = (char*)d_ws;
    int*   indices = (int*)ws;                                   // N ints
    float* cbsqr   = (float*)(ws + (size_t)N * 4);               // K
    float* pval    = cbsqr + K_CODES;                            // N*NPART
    int*   pidx    = (int*)(pval + (size_t)N * NPART);           // N*NPART
    float* counts  = (float*)(pidx + (size_t)N * NPART);         // K
    float* dw      = counts + K_CODES;                           // K*D
    // counts+dw are contiguous: zero them together
    const int zero_f = K_CODES + K_CODES * D_DIM;                // 525312 floats
    zero_kernel<<<(zero_f / 4 + 255) / 256, 256, 0, stream>>>((float4*)counts, zero_f / 4);

    cbsqr_kernel<<<K_CODES, 64, 0, stream>>>(codebook, cbsqr);

    dim3 g_argmin(N / BM, K_CODES / BN);   // (128, 8) = 1024 blocks
    argmin_part<<<g_argmin, 256, 0, stream>>>(z_e_x, codebook, cbsqr, pval, pidx);

    combine_kernel<<<(N + 255) / 256, 256, 0, stream>>>(pval, pidx, indices, counts, N);

    dw_kernel<<<(N * (D_DIM / 4)) / 256, 256, 0, stream>>>(z_e_x, indices, dw);

    finalize_kernel<<<(K_CODES * (D_DIM / 4)) / 256, 256, 0, stream>>>(
        ema_count, ema_w, counts, dw, new_emb, new_count, new_ema_w);

    gather_kernel<<<(N * (D_DIM / 4)) / 256, 256, 0, stream>>>(
        codebook, new_emb, indices, z_q_x, z_q_x_bar);
}

// Round 4
// 265.747 us; speedup vs baseline: 1.8629x; 1.4822x over previous
//
#include <hip/hip_runtime.h>

typedef _Float16 half8  __attribute__((ext_vector_type(8)));
typedef _Float16 half4v __attribute__((ext_vector_type(4)));
typedef float    f32x4  __attribute__((ext_vector_type(4)));

constexpr int K_CODES = 1024;
constexpr int D_DIM   = 512;
constexpr float DECAY = 0.99f;
constexpr float OMD   = 0.01f;
constexpr float LO_SCALE = 2048.0f;       // 2^11: keeps lo in normal f16 range
constexpr float INV_LO   = 1.0f / 2048.0f;

constexpr int BM = 128;
constexpr int BN = 128;
constexpr int BK = 32;
constexpr int NPART = K_CODES / BN;       // 8

// ---------------------------------------------------------------------------
// zero-fill dw region (runs AFTER argmin — bh/bl alias this space before)
__global__ __launch_bounds__(256) void zero_kernel(float4* __restrict__ p, int n4) {
    int i = blockIdx.x * 256 + threadIdx.x;
    if (i < n4) p[i] = make_float4(0.f, 0.f, 0.f, 0.f);
}

// ---------------------------------------------------------------------------
// cb_sqr[k] = sum_d codebook[k][d]^2 ; also zeroes counts[k]
__global__ __launch_bounds__(64) void cbsqr_kernel(const float* __restrict__ cb,
                                                   float* __restrict__ out,
                                                   float* __restrict__ counts) {
    int k = blockIdx.x;
    int lane = threadIdx.x;
    float s = 0.f;
    for (int d = lane; d < D_DIM; d += 64) {
        float v = cb[(size_t)k * D_DIM + d];
        s += v * v;
    }
    #pragma unroll
    for (int off = 32; off > 0; off >>= 1) s += __shfl_down(s, off);
    if (lane == 0) { out[k] = s; counts[k] = 0.f; }
}

// ---------------------------------------------------------------------------
// codebook -> f16 hi + scaled f16 lo   (x ~= hi + lo/2048)
__global__ __launch_bounds__(256)
void splitB_kernel(const float* __restrict__ cb,
                   _Float16* __restrict__ bh, _Float16* __restrict__ bl) {
    int i = blockIdx.x * 256 + threadIdx.x;    // over K*D/4
    f32x4 v = reinterpret_cast<const f32x4*>(cb)[i];
    half4v h, l;
    #pragma unroll
    for (int j = 0; j < 4; ++j) {
        _Float16 hh = (_Float16)v[j];
        h[j] = hh;
        l[j] = (_Float16)((v[j] - (float)hh) * LO_SCALE);
    }
    reinterpret_cast<half4v*>(bh)[i] = h;
    reinterpret_cast<half4v*>(bl)[i] = l;
}

// ---------------------------------------------------------------------------
// MFMA argmin over one 128-col slice. dist = cbsqr[c] - 2*dot(x,c), with
// dot = Ahi.Bhi + (Ahi.Blo + Alo.Bhi)/2048 via mfma_f32_16x16x32_f16.
// A staged fp32 in LDS (hi/lo split in registers); B hi/lo staged f16.
// All LDS tiles XOR-chunk-swizzled via pre-swizzled global_load_lds sources.
// Each 64x64 wave-quadrant computes a partial argmin; the two column-half
// waves are combined through LDS (sv/si) before the single per-row write —
// the r3 bug was both halves racing on the same pval slot.
__global__ __launch_bounds__(256, 2)
void argmin_mfma(const float* __restrict__ A,        // [N, D]
                 const _Float16* __restrict__ Bh,    // [K, D]
                 const _Float16* __restrict__ Bl,    // [K, D]
                 const float* __restrict__ cbsqr,    // [K]
                 float* __restrict__ pval,           // [N, NPART]
                 int*   __restrict__ pidx) {         // [N, NPART]
    __shared__ float    As[BM * BK];      // 16 KiB: [128 rows][32 k] fp32
    __shared__ _Float16 Bhs[BN * BK];     // 8 KiB:  [128 rows][32 k] f16
    __shared__ _Float16 Bls[BN * BK];     // 8 KiB
    __shared__ float    sv[2][BM];        // cross-wave argmin combine
    __shared__ int      si[2][BM];

    const int tid  = threadIdx.x;
    const int lane = tid & 63;
    const int wid  = tid >> 6;
    const int wr = wid >> 1, wc = wid & 1;     // wave -> 64x64 quadrant
    const int lq = lane >> 4;                  // k-chunk select
    const int lr = lane & 15;                  // row/col within fragment

    const int row0  = blockIdx.x * BM;
    const int cbase = blockIdx.y * BN;

    f32x4 acc_h[4][4], acc_c[4][4];
    #pragma unroll
    for (int m = 0; m < 4; ++m)
        #pragma unroll
        for (int n = 0; n < 4; ++n) {
            acc_h[m][n] = f32x4{0.f, 0.f, 0.f, 0.f};
            acc_c[m][n] = f32x4{0.f, 0.f, 0.f, 0.f};
        }

    for (int d0 = 0; d0 < D_DIM; d0 += BK) {
        // --- stage A fp32: rows are 128B = eight 16B chunks; store chunk c of
        // row r at position c ^ (r&7)  (inverse-swizzled source, linear dest)
        #pragma unroll
        for (int it = 0; it < 4; ++it) {
            int p = it * 4096 + wid * 1024 + lane * 16;    // dest byte pos
            int row  = p >> 7;
            int cpos = (p >> 4) & 7;
            int sc   = cpos ^ (row & 7);
            const float* src = A + (size_t)(row0 + row) * D_DIM + d0 + sc * 4;
            __builtin_amdgcn_global_load_lds(
                (const __attribute__((address_space(1))) void*)src,
                (__attribute__((address_space(3))) void*)(As + it * 1024 + wid * 256),
                16, 0, 0);
        }
        // --- stage Bh/Bl f16: rows are 64B = four 16B chunks; swz = (r^(r>>2))&3
        #pragma unroll
        for (int it = 0; it < 2; ++it) {
            int p = it * 4096 + wid * 1024 + lane * 16;
            int row  = p >> 6;
            int cpos = (p >> 4) & 3;
            int sc   = cpos ^ ((row ^ (row >> 2)) & 3);
            size_t goff = (size_t)(cbase + row) * D_DIM + d0 + sc * 8;
            __builtin_amdgcn_global_load_lds(
                (const __attribute__((address_space(1))) void*)(Bh + goff),
                (__attribute__((address_space(3))) void*)(Bhs + it * 2048 + wid * 512),
                16, 0, 0);
            __builtin_amdgcn_global_load_lds(
                (const __attribute__((address_space(1))) void*)(Bl + goff),
                (__attribute__((address_space(3))) void*)(Bls + it * 2048 + wid * 512),
                16, 0, 0);
        }
        __syncthreads();   // drains vmcnt (compiler) — LDS tiles ready

        // --- B fragments: lane holds col (l&15), k = lq*8..lq*8+7
        half8 bh[4], bl[4];
        #pragma unroll
        for (int n = 0; n < 4; ++n) {
            int rB  = wc * 64 + n * 16 + lr;
            int pos = lq ^ ((rB ^ (rB >> 2)) & 3);
            bh[n] = *reinterpret_cast<const half8*>(&Bhs[rB * 32 + pos * 8]);
            bl[n] = *reinterpret_cast<const half8*>(&Bls[rB * 32 + pos * 8]);
        }
        // --- A fragments: read fp32, split hi/lo in regs, 3 MFMA per (m,n)
        #pragma unroll
        for (int m = 0; m < 4; ++m) {
            int rA = wr * 64 + m * 16 + lr;
            int p0 = (2 * lq)     ^ (rA & 7);
            int p1 = (2 * lq + 1) ^ (rA & 7);
            f32x4 a0 = *reinterpret_cast<const f32x4*>(&As[rA * 32 + p0 * 4]);
            f32x4 a1 = *reinterpret_cast<const f32x4*>(&As[rA * 32 + p1 * 4]);
            half8 ah, al;
            #pragma unroll
            for (int j = 0; j < 4; ++j) {
                _Float16 h = (_Float16)a0[j];
                ah[j] = h;
                al[j] = (_Float16)((a0[j] - (float)h) * LO_SCALE);
            }
            #pragma unroll
            for (int j = 0; j < 4; ++j) {
                _Float16 h = (_Float16)a1[j];
                ah[4 + j] = h;
                al[4 + j] = (_Float16)((a1[j] - (float)h) * LO_SCALE);
            }
            #pragma unroll
            for (int n = 0; n < 4; ++n) {
                acc_h[m][n] = __builtin_amdgcn_mfma_f32_16x16x32_f16(ah, bh[n], acc_h[m][n], 0, 0, 0);
                acc_c[m][n] = __builtin_amdgcn_mfma_f32_16x16x32_f16(ah, bl[n], acc_c[m][n], 0, 0, 0);
                acc_c[m][n] = __builtin_amdgcn_mfma_f32_16x16x32_f16(al, bh[n], acc_c[m][n], 0, 0, 0);
            }
        }
        __syncthreads();
    }

    // --- fused argmin epilogue.
    // C/D layout: col = lane&15, row = lq*4 + reg  (m89, dtype-independent)
    float cs[4];
    #pragma unroll
    for (int n = 0; n < 4; ++n) cs[n] = cbsqr[cbase + wc * 64 + n * 16 + lr];

    #pragma unroll
    for (int m = 0; m < 4; ++m) {
        #pragma unroll
        for (int q = 0; q < 4; ++q) {
            float bv = 3.4e38f;
            int   bi = 0;
            #pragma unroll
            for (int n = 0; n < 4; ++n) {    // ascending col: strict '<' = first min
                float d = cs[n] - 2.0f * acc_h[m][n][q] - (2.0f * INV_LO) * acc_c[m][n][q];
                int   c = cbase + wc * 64 + n * 16 + lr;
                if (d < bv) { bv = d; bi = c; }
            }
            // reduce across the 16 col-lanes (same rows), index tie-break
            #pragma unroll
            for (int off = 1; off < 16; off <<= 1) {
                float v2 = __shfl_xor(bv, off);
                int   i2 = __shfl_xor(bi, off);
                if (v2 < bv || (v2 == bv && i2 < bi)) { bv = v2; bi = i2; }
            }
            if (lr == 0) {
                int prow = wr * 64 + m * 16 + lq * 4 + q;   // 0..127 in block
                sv[wc][prow] = bv;
                si[wc][prow] = bi;
            }
        }
    }
    // combine the two column-half waves, ONE write per row (fixes r3 race)
    __syncthreads();
    if (tid < BM) {
        float v0 = sv[0][tid], v1 = sv[1][tid];
        int   i0 = si[0][tid], i1 = si[1][tid];
        // wc=0 covers smaller col indices: on tie keep i0 (first occurrence)
        float bv = (v1 < v0) ? v1 : v0;
        int   bi = (v1 < v0) ? i1 : i0;
        pval[(size_t)(row0 + tid) * NPART + blockIdx.y] = bv;
        pidx[(size_t)(row0 + tid) * NPART + blockIdx.y] = bi;
    }
}

// ---------------------------------------------------------------------------
// combine the NPART K-slices, emit final index, accumulate counts
__global__ __launch_bounds__(256)
void combine_kernel(const float* __restrict__ pval, const int* __restrict__ pidx,
                    int* __restrict__ indices, float* __restrict__ counts, int N) {
    int r = blockIdx.x * 256 + threadIdx.x;
    if (r >= N) return;
    float bv = pval[(size_t)r * NPART];
    int   bi = pidx[(size_t)r * NPART];
    #pragma unroll
    for (int p = 1; p < NPART; ++p) {
        float v = pval[(size_t)r * NPART + p];
        int  ii = pidx[(size_t)r * NPART + p];
        if (v < bv) { bv = v; bi = ii; }   // ascending col-blocks: '<' = first min
    }
    indices[r] = bi;
    atomicAdd(&counts[bi], 1.0f);
}

// ---------------------------------------------------------------------------
__global__ __launch_bounds__(256)
void dw_kernel(const float* __restrict__ flat, const int* __restrict__ indices,
               float* __restrict__ dw) {
    int gid = blockIdx.x * 256 + threadIdx.x;   // N*D/4 threads
    int r = gid >> 7;
    int d = (gid & 127) * 4;
    int k = indices[r];
    float4 v = *reinterpret_cast<const float4*>(&flat[(size_t)r * D_DIM + d]);
    float* p = &dw[(size_t)k * D_DIM + d];
    atomicAdd(p + 0, v.x);
    atomicAdd(p + 1, v.y);
    atomicAdd(p + 2, v.z);
    atomicAdd(p + 3, v.w);
}

// ---------------------------------------------------------------------------
__global__ __launch_bounds__(256)
void finalize_kernel(const float* __restrict__ ema_count, const float* __restrict__ ema_w,
                     const float* __restrict__ counts, const float* __restrict__ dw,
                     float* __restrict__ new_emb, float* __restrict__ new_count,
                     float* __restrict__ new_ema_w) {
    int gid = blockIdx.x * 256 + threadIdx.x;   // K*D/4 threads
    int k = gid >> 7;
    int d = (gid & 127) * 4;
    float nc = DECAY * ema_count[k] + OMD * counts[k];
    size_t off = (size_t)k * D_DIM + d;
    float4 w  = *reinterpret_cast<const float4*>(&ema_w[off]);
    float4 dv = *reinterpret_cast<const float4*>(&dw[off]);
    float4 nw;
    nw.x = DECAY * w.x + OMD * dv.x;
    nw.y = DECAY * w.y + OMD * dv.y;
    nw.z = DECAY * w.z + OMD * dv.z;
    nw.w = DECAY * w.w + OMD * dv.w;
    *reinterpret_cast<float4*>(&new_ema_w[off]) = nw;
    float inv = 1.0f / nc;
    float4 ne;
    ne.x = nw.x * inv; ne.y = nw.y * inv; ne.z = nw.z * inv; ne.w = nw.w * inv;
    *reinterpret_cast<float4*>(&new_emb[off]) = ne;
    if ((gid & 127) == 0) new_count[k] = nc;
}

// ---------------------------------------------------------------------------
__global__ __launch_bounds__(256)
void gather_kernel(const float* __restrict__ codebook, const float* __restrict__ new_emb,
                   const int* __restrict__ indices,
                   float* __restrict__ zq, float* __restrict__ zqb) {
    int gid = blockIdx.x * 256 + threadIdx.x;   // N*D/4 threads
    int r = gid >> 7;
    int d = (gid & 127) * 4;
    int k = indices[r];
    size_t src = (size_t)k * D_DIM + d;
    size_t dst = (size_t)r * D_DIM + d;
    *reinterpret_cast<float4*>(&zq[dst])  = *reinterpret_cast<const float4*>(&codebook[src]);
    *reinterpret_cast<float4*>(&zqb[dst]) = *reinterpret_cast<const float4*>(&new_emb[src]);
}

// ---------------------------------------------------------------------------
extern "C" void kernel_launch(void* const* d_in, const int* in_sizes, int n_in,
                              void* d_out, int out_size, void* d_ws, size_t ws_size,
                              hipStream_t stream) {
    const float* z_e_x     = (const float*)d_in[0];
    const float* codebook  = (const float*)d_in[1];
    const float* ema_count = (const float*)d_in[2];
    const float* ema_w     = (const float*)d_in[3];

    const int N = in_sizes[0] / D_DIM;   // 16384

    float* out = (float*)d_out;
    float* z_q_x     = out;
    float* z_q_x_bar = z_q_x + (size_t)N * D_DIM;
    float* new_emb   = z_q_x_bar + (size_t)N * D_DIM;
    float* new_count = new_emb + (size_t)K_CODES * D_DIM;
    float* new_ema_w = new_count + K_CODES;

    // workspace layout: indices | cbsqr | pval | pidx | counts | dw
    // bh/bl (f16 codebook splits, 2 MB total) ALIAS the dw region: they are
    // consumed by argmin, then dw is zeroed and reused. Zero ws growth.
    char* ws = (char*)d_ws;
    int*   indices = (int*)ws;                                   // N ints
    float* cbsqr   = (float*)(ws + (size_t)N * 4);               // K
    float* pval    = cbsqr + K_CODES;                            // N*NPART
    int*   pidx    = (int*)(pval + (size_t)N * NPART);           // N*NPART
    float* counts  = (float*)(pidx + (size_t)N * NPART);         // K
    float* dw      = counts + K_CODES;                           // K*D
    _Float16* bh   = (_Float16*)dw;                              // K*D f16
    _Float16* bl   = bh + (size_t)K_CODES * D_DIM;               // K*D f16

    cbsqr_kernel<<<K_CODES, 64, 0, stream>>>(codebook, cbsqr, counts);
    splitB_kernel<<<(K_CODES * D_DIM / 4) / 256, 256, 0, stream>>>(codebook, bh, bl);

    dim3 g_argmin(N / BM, K_CODES / BN);   // (128, 8) — x fastest: col-block-major
    argmin_mfma<<<g_argmin, 256, 0, stream>>>(z_e_x, bh, bl, cbsqr, pval, pidx);

    combine_kernel<<<(N + 255) / 256, 256, 0, stream>>>(pval, pidx, indices, counts, N);

    // now bh/bl dead -> zero dw region and accumulate
    zero_kernel<<<(K_CODES * D_DIM / 4) / 256, 256, 0, stream>>>((float4*)dw, K_CODES * D_DIM / 4);

    dw_kernel<<<(N * (D_DIM / 4)) / 256, 256, 0, stream>>>(z_e_x, indices, dw);

    finalize_kernel<<<(K_CODES * (D_DIM / 4)) / 256, 256, 0, stream>>>(
        ema_count, ema_w, counts, dw, new_emb, new_count, new_ema_w);

    gather_kernel<<<(N * (D_DIM / 4)) / 256, 256, 0, stream>>>(
        codebook, new_emb, indices, z_q_x, z_q_x_bar);
}

// Round 5
// 254.805 us; speedup vs baseline: 1.9429x; 1.0429x over previous
//
#include <hip/hip_runtime.h>

typedef _Float16 half8  __attribute__((ext_vector_type(8)));
typedef _Float16 half4v __attribute__((ext_vector_type(4)));
typedef float    f32x4  __attribute__((ext_vector_type(4)));

constexpr int K_CODES = 1024;
constexpr int D_DIM   = 512;
constexpr float DECAY = 0.99f;
constexpr float OMD   = 0.01f;
constexpr float LO_SCALE = 2048.0f;       // 2^11: keeps lo in normal f16 range
constexpr float INV_LO   = 1.0f / 2048.0f;

constexpr int BM = 128;
constexpr int BN = 128;
constexpr int BK = 32;
constexpr int NPART = K_CODES / BN;       // 8

// ---------------------------------------------------------------------------
// cb_sqr[k] = sum_d codebook[k][d]^2 ; also zeroes counts[k]
__global__ __launch_bounds__(64) void cbsqr_kernel(const float* __restrict__ cb,
                                                   float* __restrict__ out,
                                                   float* __restrict__ counts) {
    int k = blockIdx.x;
    int lane = threadIdx.x;
    float s = 0.f;
    for (int d = lane; d < D_DIM; d += 64) {
        float v = cb[(size_t)k * D_DIM + d];
        s += v * v;
    }
    #pragma unroll
    for (int off = 32; off > 0; off >>= 1) s += __shfl_down(s, off);
    if (lane == 0) { out[k] = s; counts[k] = 0.f; }
}

// ---------------------------------------------------------------------------
// codebook -> f16 hi + scaled f16 lo   (x ~= hi + lo/2048)
__global__ __launch_bounds__(256)
void splitB_kernel(const float* __restrict__ cb,
                   _Float16* __restrict__ bh, _Float16* __restrict__ bl) {
    int i = blockIdx.x * 256 + threadIdx.x;    // over K*D/4
    f32x4 v = reinterpret_cast<const f32x4*>(cb)[i];
    half4v h, l;
    #pragma unroll
    for (int j = 0; j < 4; ++j) {
        _Float16 hh = (_Float16)v[j];
        h[j] = hh;
        l[j] = (_Float16)((v[j] - (float)hh) * LO_SCALE);
    }
    reinterpret_cast<half4v*>(bh)[i] = h;
    reinterpret_cast<half4v*>(bl)[i] = l;
}

// ---------------------------------------------------------------------------
// MFMA argmin over one 128-col slice. dist = cbsqr[c] - 2*dot(x,c), with
// dot = Ahi.Bhi + (Ahi.Blo + Alo.Bhi)/2048 via mfma_f32_16x16x32_f16.
// A staged fp32 in LDS (hi/lo split in registers); B hi/lo staged f16.
// All LDS tiles XOR-chunk-swizzled via pre-swizzled global_load_lds sources.
// The two column-half waves combine through LDS before the per-row write.
__global__ __launch_bounds__(256, 2)
void argmin_mfma(const float* __restrict__ A,        // [N, D]
                 const _Float16* __restrict__ Bh,    // [K, D]
                 const _Float16* __restrict__ Bl,    // [K, D]
                 const float* __restrict__ cbsqr,    // [K]
                 float* __restrict__ pval,           // [N, NPART]
                 int*   __restrict__ pidx) {         // [N, NPART]
    __shared__ float    As[BM * BK];      // 16 KiB: [128 rows][32 k] fp32
    __shared__ _Float16 Bhs[BN * BK];     // 8 KiB:  [128 rows][32 k] f16
    __shared__ _Float16 Bls[BN * BK];     // 8 KiB
    __shared__ float    sv[2][BM];        // cross-wave argmin combine
    __shared__ int      si[2][BM];

    const int tid  = threadIdx.x;
    const int lane = tid & 63;
    const int wid  = tid >> 6;
    const int wr = wid >> 1, wc = wid & 1;     // wave -> 64x64 quadrant
    const int lq = lane >> 4;                  // k-chunk select
    const int lr = lane & 15;                  // row/col within fragment

    const int row0  = blockIdx.x * BM;
    const int cbase = blockIdx.y * BN;

    f32x4 acc_h[4][4], acc_c[4][4];
    #pragma unroll
    for (int m = 0; m < 4; ++m)
        #pragma unroll
        for (int n = 0; n < 4; ++n) {
            acc_h[m][n] = f32x4{0.f, 0.f, 0.f, 0.f};
            acc_c[m][n] = f32x4{0.f, 0.f, 0.f, 0.f};
        }

    for (int d0 = 0; d0 < D_DIM; d0 += BK) {
        // --- stage A fp32: rows are 128B = eight 16B chunks; store chunk c of
        // row r at position c ^ (r&7)  (inverse-swizzled source, linear dest)
        #pragma unroll
        for (int it = 0; it < 4; ++it) {
            int p = it * 4096 + wid * 1024 + lane * 16;    // dest byte pos
            int row  = p >> 7;
            int cpos = (p >> 4) & 7;
            int sc   = cpos ^ (row & 7);
            const float* src = A + (size_t)(row0 + row) * D_DIM + d0 + sc * 4;
            __builtin_amdgcn_global_load_lds(
                (const __attribute__((address_space(1))) void*)src,
                (__attribute__((address_space(3))) void*)(As + it * 1024 + wid * 256),
                16, 0, 0);
        }
        // --- stage Bh/Bl f16: rows are 64B = four 16B chunks; swz = (r^(r>>2))&3
        #pragma unroll
        for (int it = 0; it < 2; ++it) {
            int p = it * 4096 + wid * 1024 + lane * 16;
            int row  = p >> 6;
            int cpos = (p >> 4) & 3;
            int sc   = cpos ^ ((row ^ (row >> 2)) & 3);
            size_t goff = (size_t)(cbase + row) * D_DIM + d0 + sc * 8;
            __builtin_amdgcn_global_load_lds(
                (const __attribute__((address_space(1))) void*)(Bh + goff),
                (__attribute__((address_space(3))) void*)(Bhs + it * 2048 + wid * 512),
                16, 0, 0);
            __builtin_amdgcn_global_load_lds(
                (const __attribute__((address_space(1))) void*)(Bl + goff),
                (__attribute__((address_space(3))) void*)(Bls + it * 2048 + wid * 512),
                16, 0, 0);
        }
        __syncthreads();   // drains vmcnt (compiler) — LDS tiles ready

        // --- B fragments: lane holds col (l&15), k = lq*8..lq*8+7
        half8 bh[4], bl[4];
        #pragma unroll
        for (int n = 0; n < 4; ++n) {
            int rB  = wc * 64 + n * 16 + lr;
            int pos = lq ^ ((rB ^ (rB >> 2)) & 3);
            bh[n] = *reinterpret_cast<const half8*>(&Bhs[rB * 32 + pos * 8]);
            bl[n] = *reinterpret_cast<const half8*>(&Bls[rB * 32 + pos * 8]);
        }
        // --- A fragments: read fp32, split hi/lo in regs, 3 MFMA per (m,n)
        #pragma unroll
        for (int m = 0; m < 4; ++m) {
            int rA = wr * 64 + m * 16 + lr;
            int p0 = (2 * lq)     ^ (rA & 7);
            int p1 = (2 * lq + 1) ^ (rA & 7);
            f32x4 a0 = *reinterpret_cast<const f32x4*>(&As[rA * 32 + p0 * 4]);
            f32x4 a1 = *reinterpret_cast<const f32x4*>(&As[rA * 32 + p1 * 4]);
            half8 ah, al;
            #pragma unroll
            for (int j = 0; j < 4; ++j) {
                _Float16 h = (_Float16)a0[j];
                ah[j] = h;
                al[j] = (_Float16)((a0[j] - (float)h) * LO_SCALE);
            }
            #pragma unroll
            for (int j = 0; j < 4; ++j) {
                _Float16 h = (_Float16)a1[j];
                ah[4 + j] = h;
                al[4 + j] = (_Float16)((a1[j] - (float)h) * LO_SCALE);
            }
            #pragma unroll
            for (int n = 0; n < 4; ++n) {
                acc_h[m][n] = __builtin_amdgcn_mfma_f32_16x16x32_f16(ah, bh[n], acc_h[m][n], 0, 0, 0);
                acc_c[m][n] = __builtin_amdgcn_mfma_f32_16x16x32_f16(ah, bl[n], acc_c[m][n], 0, 0, 0);
                acc_c[m][n] = __builtin_amdgcn_mfma_f32_16x16x32_f16(al, bh[n], acc_c[m][n], 0, 0, 0);
            }
        }
        __syncthreads();
    }

    // --- fused argmin epilogue.
    // C/D layout: col = lane&15, row = lq*4 + reg  (m89, dtype-independent)
    float cs[4];
    #pragma unroll
    for (int n = 0; n < 4; ++n) cs[n] = cbsqr[cbase + wc * 64 + n * 16 + lr];

    #pragma unroll
    for (int m = 0; m < 4; ++m) {
        #pragma unroll
        for (int q = 0; q < 4; ++q) {
            float bv = 3.4e38f;
            int   bi = 0;
            #pragma unroll
            for (int n = 0; n < 4; ++n) {    // ascending col: strict '<' = first min
                float d = cs[n] - 2.0f * acc_h[m][n][q] - (2.0f * INV_LO) * acc_c[m][n][q];
                int   c = cbase + wc * 64 + n * 16 + lr;
                if (d < bv) { bv = d; bi = c; }
            }
            // reduce across the 16 col-lanes (same rows), index tie-break
            #pragma unroll
            for (int off = 1; off < 16; off <<= 1) {
                float v2 = __shfl_xor(bv, off);
                int   i2 = __shfl_xor(bi, off);
                if (v2 < bv || (v2 == bv && i2 < bi)) { bv = v2; bi = i2; }
            }
            if (lr == 0) {
                int prow = wr * 64 + m * 16 + lq * 4 + q;   // 0..127 in block
                sv[wc][prow] = bv;
                si[wc][prow] = bi;
            }
        }
    }
    // combine the two column-half waves, ONE write per row
    __syncthreads();
    if (tid < BM) {
        float v0 = sv[0][tid], v1 = sv[1][tid];
        int   i0 = si[0][tid], i1 = si[1][tid];
        // wc=0 covers smaller col indices: on tie keep i0 (first occurrence)
        float bv = (v1 < v0) ? v1 : v0;
        int   bi = (v1 < v0) ? i1 : i0;
        pval[(size_t)(row0 + tid) * NPART + blockIdx.y] = bv;
        pidx[(size_t)(row0 + tid) * NPART + blockIdx.y] = bi;
    }
}

// ---------------------------------------------------------------------------
// combine the NPART K-slices, emit final index, accumulate counts
__global__ __launch_bounds__(256)
void combine_kernel(const float* __restrict__ pval, const int* __restrict__ pidx,
                    int* __restrict__ indices, float* __restrict__ counts, int N) {
    int r = blockIdx.x * 256 + threadIdx.x;
    if (r >= N) return;
    float bv = pval[(size_t)r * NPART];
    int   bi = pidx[(size_t)r * NPART];
    #pragma unroll
    for (int p = 1; p < NPART; ++p) {
        float v = pval[(size_t)r * NPART + p];
        int  ii = pidx[(size_t)r * NPART + p];
        if (v < bv) { bv = v; bi = ii; }   // ascending col-blocks: '<' = first min
    }
    indices[r] = bi;
    atomicAdd(&counts[bi], 1.0f);
}

// ---------------------------------------------------------------------------
// exclusive prefix sum of counts[K] -> offs[K] (+ offs[K]=N), cursor = offs
// single block, 256 threads x 4 codes each
__global__ __launch_bounds__(256)
void scan_kernel(const float* __restrict__ counts,
                 int* __restrict__ offs, int* __restrict__ cursor) {
    __shared__ int part[256];
    int t = threadIdx.x;
    int c[4], s = 0;
    #pragma unroll
    for (int j = 0; j < 4; ++j) { c[j] = (int)counts[t * 4 + j]; s += c[j]; }
    part[t] = s;
    __syncthreads();
    // Hillis-Steele inclusive scan over the 256 partials
    for (int off = 1; off < 256; off <<= 1) {
        int v   = part[t];
        int add = (t >= off) ? part[t - off] : 0;
        __syncthreads();
        part[t] = v + add;
        __syncthreads();
    }
    int run = part[t] - s;   // exclusive offset for this thread's first code
    #pragma unroll
    for (int j = 0; j < 4; ++j) {
        offs[t * 4 + j]   = run;
        cursor[t * 4 + j] = run;
        run += c[j];
    }
    if (t == 255) offs[K_CODES] = part[255];
}

// ---------------------------------------------------------------------------
// bucket rows by code: rowlist[offs[k]..offs[k+1]) = rows with indices==k
__global__ __launch_bounds__(256)
void scatter_kernel(const int* __restrict__ indices, int* __restrict__ cursor,
                    int* __restrict__ rowlist, int N) {
    int r = blockIdx.x * 256 + threadIdx.x;
    if (r >= N) return;
    int k = indices[r];
    int pos = atomicAdd(&cursor[k], 1);
    rowlist[pos] = r;
}

// ---------------------------------------------------------------------------
// per-code segmented sum of flat rows + fused EMA finalize.
// one 128-thread block per code; thread t owns float4 at d = t*4.
__global__ __launch_bounds__(128)
void dwsum_kernel(const float* __restrict__ flat, const int* __restrict__ rowlist,
                  const int* __restrict__ offs, const float* __restrict__ counts,
                  const float* __restrict__ ema_count, const float* __restrict__ ema_w,
                  float* __restrict__ new_emb, float* __restrict__ new_count,
                  float* __restrict__ new_ema_w) {
    int k = blockIdx.x;
    int t = threadIdx.x;
    int beg = offs[k], end = offs[k + 1];
    f32x4 acc = {0.f, 0.f, 0.f, 0.f};
    for (int i = beg; i < end; ++i) {
        int r = rowlist[i];
        f32x4 v = *reinterpret_cast<const f32x4*>(&flat[(size_t)r * D_DIM + t * 4]);
        acc[0] += v[0]; acc[1] += v[1]; acc[2] += v[2]; acc[3] += v[3];
    }
    float nc = DECAY * ema_count[k] + OMD * counts[k];
    size_t off = (size_t)k * D_DIM + t * 4;
    f32x4 w = *reinterpret_cast<const f32x4*>(&ema_w[off]);
    f32x4 nw, ne;
    float inv = 1.0f / nc;
    #pragma unroll
    for (int j = 0; j < 4; ++j) {
        nw[j] = DECAY * w[j] + OMD * acc[j];
        ne[j] = nw[j] * inv;
    }
    *reinterpret_cast<f32x4*>(&new_ema_w[off]) = nw;
    *reinterpret_cast<f32x4*>(&new_emb[off])   = ne;
    if (t == 0) new_count[k] = nc;
}

// ---------------------------------------------------------------------------
__global__ __launch_bounds__(256)
void gather_kernel(const float* __restrict__ codebook, const float* __restrict__ new_emb,
                   const int* __restrict__ indices,
                   float* __restrict__ zq, float* __restrict__ zqb) {
    int gid = blockIdx.x * 256 + threadIdx.x;   // N*D/4 threads
    int r = gid >> 7;
    int d = (gid & 127) * 4;
    int k = indices[r];
    size_t src = (size_t)k * D_DIM + d;
    size_t dst = (size_t)r * D_DIM + d;
    *reinterpret_cast<float4*>(&zq[dst])  = *reinterpret_cast<const float4*>(&codebook[src]);
    *reinterpret_cast<float4*>(&zqb[dst]) = *reinterpret_cast<const float4*>(&new_emb[src]);
}

// ---------------------------------------------------------------------------
extern "C" void kernel_launch(void* const* d_in, const int* in_sizes, int n_in,
                              void* d_out, int out_size, void* d_ws, size_t ws_size,
                              hipStream_t stream) {
    const float* z_e_x     = (const float*)d_in[0];
    const float* codebook  = (const float*)d_in[1];
    const float* ema_count = (const float*)d_in[2];
    const float* ema_w     = (const float*)d_in[3];

    const int N = in_sizes[0] / D_DIM;   // 16384

    float* out = (float*)d_out;
    float* z_q_x     = out;
    float* z_q_x_bar = z_q_x + (size_t)N * D_DIM;
    float* new_emb   = z_q_x_bar + (size_t)N * D_DIM;
    float* new_count = new_emb + (size_t)K_CODES * D_DIM;
    float* new_ema_w = new_count + K_CODES;

    // workspace: indices | cbsqr | pval | pidx | counts | bh/bl | offs | cursor | rowlist
    char* ws = (char*)d_ws;
    int*   indices = (int*)ws;                                   // N ints
    float* cbsqr   = (float*)(ws + (size_t)N * 4);               // K
    float* pval    = cbsqr + K_CODES;                            // N*NPART
    int*   pidx    = (int*)(pval + (size_t)N * NPART);           // N*NPART
    float* counts  = (float*)(pidx + (size_t)N * NPART);         // K
    _Float16* bh   = (_Float16*)(counts + K_CODES);              // K*D f16
    _Float16* bl   = bh + (size_t)K_CODES * D_DIM;               // K*D f16
    int*   offs    = (int*)(bl + (size_t)K_CODES * D_DIM);       // K+1 ints
    int*   cursor  = offs + K_CODES + 1;                         // K ints
    int*   rowlist = cursor + K_CODES;                           // N ints

    cbsqr_kernel<<<K_CODES, 64, 0, stream>>>(codebook, cbsqr, counts);
    splitB_kernel<<<(K_CODES * D_DIM / 4) / 256, 256, 0, stream>>>(codebook, bh, bl);

    dim3 g_argmin(N / BM, K_CODES / BN);   // (128, 8) — x fastest: col-block-major
    argmin_mfma<<<g_argmin, 256, 0, stream>>>(z_e_x, bh, bl, cbsqr, pval, pidx);

    combine_kernel<<<(N + 255) / 256, 256, 0, stream>>>(pval, pidx, indices, counts, N);

    scan_kernel<<<1, 256, 0, stream>>>(counts, offs, cursor);
    scatter_kernel<<<(N + 255) / 256, 256, 0, stream>>>(indices, cursor, rowlist, N);

    dwsum_kernel<<<K_CODES, 128, 0, stream>>>(z_e_x, rowlist, offs, counts,
                                              ema_count, ema_w,
                                              new_emb, new_count, new_ema_w);

    gather_kernel<<<(N * (D_DIM / 4)) / 256, 256, 0, stream>>>(
        codebook, new_emb, indices, z_q_x, z_q_x_bar);
}

// Round 6
// 139.337 us; speedup vs baseline: 3.5529x; 1.8287x over previous
//
#include <hip/hip_runtime.h>

typedef _Float16 half8  __attribute__((ext_vector_type(8)));
typedef _Float16 half4v __attribute__((ext_vector_type(4)));
typedef float    f32x4  __attribute__((ext_vector_type(4)));

constexpr int K_CODES = 1024;
constexpr int D_DIM   = 512;
constexpr float DECAY = 0.99f;
constexpr float OMD   = 0.01f;
constexpr float LO_SCALE = 2048.0f;       // 2^11: keeps lo in normal f16 range
constexpr float INV_LO   = 1.0f / 2048.0f;

constexpr int BM = 128;
constexpr int BN = 128;
constexpr int BK = 32;
constexpr int NPART = K_CODES / BN;       // 8
constexpr int CHUNK = 32;                 // rowlist entries per chunksum block

// ---------------------------------------------------------------------------
// zero-fill dw region (aliases dead bh/bl after argmin)
__global__ __launch_bounds__(256) void zero_kernel(float4* __restrict__ p, int n4) {
    int i = blockIdx.x * 256 + threadIdx.x;
    if (i < n4) p[i] = make_float4(0.f, 0.f, 0.f, 0.f);
}

// ---------------------------------------------------------------------------
// cb_sqr[k] = sum_d codebook[k][d]^2 ; also zeroes counts[k]
__global__ __launch_bounds__(64) void cbsqr_kernel(const float* __restrict__ cb,
                                                   float* __restrict__ out,
                                                   float* __restrict__ counts) {
    int k = blockIdx.x;
    int lane = threadIdx.x;
    float s = 0.f;
    for (int d = lane; d < D_DIM; d += 64) {
        float v = cb[(size_t)k * D_DIM + d];
        s += v * v;
    }
    #pragma unroll
    for (int off = 32; off > 0; off >>= 1) s += __shfl_down(s, off);
    if (lane == 0) { out[k] = s; counts[k] = 0.f; }
}

// ---------------------------------------------------------------------------
// codebook -> f16 hi + scaled f16 lo   (x ~= hi + lo/2048)
__global__ __launch_bounds__(256)
void splitB_kernel(const float* __restrict__ cb,
                   _Float16* __restrict__ bh, _Float16* __restrict__ bl) {
    int i = blockIdx.x * 256 + threadIdx.x;    // over K*D/4
    f32x4 v = reinterpret_cast<const f32x4*>(cb)[i];
    half4v h, l;
    #pragma unroll
    for (int j = 0; j < 4; ++j) {
        _Float16 hh = (_Float16)v[j];
        h[j] = hh;
        l[j] = (_Float16)((v[j] - (float)hh) * LO_SCALE);
    }
    reinterpret_cast<half4v*>(bh)[i] = h;
    reinterpret_cast<half4v*>(bl)[i] = l;
}

// ---------------------------------------------------------------------------
// MFMA argmin over one 128-col slice. dist = cbsqr[c] - 2*dot(x,c), with
// dot = Ahi.Bhi + (Ahi.Blo + Alo.Bhi)/2048 via mfma_f32_16x16x32_f16.
__global__ __launch_bounds__(256, 2)
void argmin_mfma(const float* __restrict__ A,        // [N, D]
                 const _Float16* __restrict__ Bh,    // [K, D]
                 const _Float16* __restrict__ Bl,    // [K, D]
                 const float* __restrict__ cbsqr,    // [K]
                 float* __restrict__ pval,           // [N, NPART]
                 int*   __restrict__ pidx) {         // [N, NPART]
    __shared__ float    As[BM * BK];      // 16 KiB: [128 rows][32 k] fp32
    __shared__ _Float16 Bhs[BN * BK];     // 8 KiB
    __shared__ _Float16 Bls[BN * BK];     // 8 KiB
    __shared__ float    sv[2][BM];        // cross-wave argmin combine
    __shared__ int      si[2][BM];

    const int tid  = threadIdx.x;
    const int lane = tid & 63;
    const int wid  = tid >> 6;
    const int wr = wid >> 1, wc = wid & 1;     // wave -> 64x64 quadrant
    const int lq = lane >> 4;                  // k-chunk select
    const int lr = lane & 15;                  // row/col within fragment

    const int row0  = blockIdx.x * BM;
    const int cbase = blockIdx.y * BN;

    f32x4 acc_h[4][4], acc_c[4][4];
    #pragma unroll
    for (int m = 0; m < 4; ++m)
        #pragma unroll
        for (int n = 0; n < 4; ++n) {
            acc_h[m][n] = f32x4{0.f, 0.f, 0.f, 0.f};
            acc_c[m][n] = f32x4{0.f, 0.f, 0.f, 0.f};
        }

    for (int d0 = 0; d0 < D_DIM; d0 += BK) {
        // stage A fp32: rows are 128B = eight 16B chunks; chunk c of row r at
        // position c ^ (r&7)  (inverse-swizzled source, linear dest)
        #pragma unroll
        for (int it = 0; it < 4; ++it) {
            int p = it * 4096 + wid * 1024 + lane * 16;    // dest byte pos
            int row  = p >> 7;
            int cpos = (p >> 4) & 7;
            int sc   = cpos ^ (row & 7);
            const float* src = A + (size_t)(row0 + row) * D_DIM + d0 + sc * 4;
            __builtin_amdgcn_global_load_lds(
                (const __attribute__((address_space(1))) void*)src,
                (__attribute__((address_space(3))) void*)(As + it * 1024 + wid * 256),
                16, 0, 0);
        }
        // stage Bh/Bl f16: rows are 64B = four 16B chunks; swz = (r^(r>>2))&3
        #pragma unroll
        for (int it = 0; it < 2; ++it) {
            int p = it * 4096 + wid * 1024 + lane * 16;
            int row  = p >> 6;
            int cpos = (p >> 4) & 3;
            int sc   = cpos ^ ((row ^ (row >> 2)) & 3);
            size_t goff = (size_t)(cbase + row) * D_DIM + d0 + sc * 8;
            __builtin_amdgcn_global_load_lds(
                (const __attribute__((address_space(1))) void*)(Bh + goff),
                (__attribute__((address_space(3))) void*)(Bhs + it * 2048 + wid * 512),
                16, 0, 0);
            __builtin_amdgcn_global_load_lds(
                (const __attribute__((address_space(1))) void*)(Bl + goff),
                (__attribute__((address_space(3))) void*)(Bls + it * 2048 + wid * 512),
                16, 0, 0);
        }
        __syncthreads();

        half8 bh[4], bl[4];
        #pragma unroll
        for (int n = 0; n < 4; ++n) {
            int rB  = wc * 64 + n * 16 + lr;
            int pos = lq ^ ((rB ^ (rB >> 2)) & 3);
            bh[n] = *reinterpret_cast<const half8*>(&Bhs[rB * 32 + pos * 8]);
            bl[n] = *reinterpret_cast<const half8*>(&Bls[rB * 32 + pos * 8]);
        }
        #pragma unroll
        for (int m = 0; m < 4; ++m) {
            int rA = wr * 64 + m * 16 + lr;
            int p0 = (2 * lq)     ^ (rA & 7);
            int p1 = (2 * lq + 1) ^ (rA & 7);
            f32x4 a0 = *reinterpret_cast<const f32x4*>(&As[rA * 32 + p0 * 4]);
            f32x4 a1 = *reinterpret_cast<const f32x4*>(&As[rA * 32 + p1 * 4]);
            half8 ah, al;
            #pragma unroll
            for (int j = 0; j < 4; ++j) {
                _Float16 h = (_Float16)a0[j];
                ah[j] = h;
                al[j] = (_Float16)((a0[j] - (float)h) * LO_SCALE);
            }
            #pragma unroll
            for (int j = 0; j < 4; ++j) {
                _Float16 h = (_Float16)a1[j];
                ah[4 + j] = h;
                al[4 + j] = (_Float16)((a1[j] - (float)h) * LO_SCALE);
            }
            #pragma unroll
            for (int n = 0; n < 4; ++n) {
                acc_h[m][n] = __builtin_amdgcn_mfma_f32_16x16x32_f16(ah, bh[n], acc_h[m][n], 0, 0, 0);
                acc_c[m][n] = __builtin_amdgcn_mfma_f32_16x16x32_f16(ah, bl[n], acc_c[m][n], 0, 0, 0);
                acc_c[m][n] = __builtin_amdgcn_mfma_f32_16x16x32_f16(al, bh[n], acc_c[m][n], 0, 0, 0);
            }
        }
        __syncthreads();
    }

    // fused argmin epilogue. C/D layout: col = lane&15, row = lq*4 + reg
    float cs[4];
    #pragma unroll
    for (int n = 0; n < 4; ++n) cs[n] = cbsqr[cbase + wc * 64 + n * 16 + lr];

    #pragma unroll
    for (int m = 0; m < 4; ++m) {
        #pragma unroll
        for (int q = 0; q < 4; ++q) {
            float bv = 3.4e38f;
            int   bi = 0;
            #pragma unroll
            for (int n = 0; n < 4; ++n) {    // ascending col: strict '<' = first min
                float d = cs[n] - 2.0f * acc_h[m][n][q] - (2.0f * INV_LO) * acc_c[m][n][q];
                int   c = cbase + wc * 64 + n * 16 + lr;
                if (d < bv) { bv = d; bi = c; }
            }
            #pragma unroll
            for (int off = 1; off < 16; off <<= 1) {
                float v2 = __shfl_xor(bv, off);
                int   i2 = __shfl_xor(bi, off);
                if (v2 < bv || (v2 == bv && i2 < bi)) { bv = v2; bi = i2; }
            }
            if (lr == 0) {
                int prow = wr * 64 + m * 16 + lq * 4 + q;   // 0..127 in block
                sv[wc][prow] = bv;
                si[wc][prow] = bi;
            }
        }
    }
    __syncthreads();
    if (tid < BM) {
        float v0 = sv[0][tid], v1 = sv[1][tid];
        int   i0 = si[0][tid], i1 = si[1][tid];
        float bv = (v1 < v0) ? v1 : v0;   // tie keeps wc=0 = smaller col
        int   bi = (v1 < v0) ? i1 : i0;
        pval[(size_t)(row0 + tid) * NPART + blockIdx.y] = bv;
        pidx[(size_t)(row0 + tid) * NPART + blockIdx.y] = bi;
    }
}

// ---------------------------------------------------------------------------
// combine the NPART K-slices, emit final index, accumulate counts
__global__ __launch_bounds__(256)
void combine_kernel(const float* __restrict__ pval, const int* __restrict__ pidx,
                    int* __restrict__ indices, float* __restrict__ counts, int N) {
    int r = blockIdx.x * 256 + threadIdx.x;
    if (r >= N) return;
    float bv = pval[(size_t)r * NPART];
    int   bi = pidx[(size_t)r * NPART];
    #pragma unroll
    for (int p = 1; p < NPART; ++p) {
        float v = pval[(size_t)r * NPART + p];
        int  ii = pidx[(size_t)r * NPART + p];
        if (v < bv) { bv = v; bi = ii; }   // ascending col-blocks: '<' = first min
    }
    indices[r] = bi;
    atomicAdd(&counts[bi], 1.0f);
}

// ---------------------------------------------------------------------------
// exclusive prefix sum of counts[K] -> offs[K] (+ offs[K]=N), cursor = offs
__global__ __launch_bounds__(256)
void scan_kernel(const float* __restrict__ counts,
                 int* __restrict__ offs, int* __restrict__ cursor) {
    __shared__ int part[256];
    int t = threadIdx.x;
    int c[4], s = 0;
    #pragma unroll
    for (int j = 0; j < 4; ++j) { c[j] = (int)counts[t * 4 + j]; s += c[j]; }
    part[t] = s;
    __syncthreads();
    for (int off = 1; off < 256; off <<= 1) {
        int v   = part[t];
        int add = (t >= off) ? part[t - off] : 0;
        __syncthreads();
        part[t] = v + add;
        __syncthreads();
    }
    int run = part[t] - s;
    #pragma unroll
    for (int j = 0; j < 4; ++j) {
        offs[t * 4 + j]   = run;
        cursor[t * 4 + j] = run;
        run += c[j];
    }
    if (t == 255) offs[K_CODES] = part[255];
}

// ---------------------------------------------------------------------------
// bucket rows by code, PACKED entries: (code<<16) | row
__global__ __launch_bounds__(256)
void scatter_kernel(const int* __restrict__ indices, int* __restrict__ cursor,
                    int* __restrict__ packed, int N) {
    int r = blockIdx.x * 256 + threadIdx.x;
    if (r >= N) return;
    int k = indices[r];
    int pos = atomicAdd(&cursor[k], 1);
    packed[pos] = (k << 16) | r;
}

// ---------------------------------------------------------------------------
// balanced segmented sum: block b owns packed[b*CHUNK .. b*CHUNK+CHUNK).
// Entries sorted by code -> flush branch is wave-uniform. Row loads issued
// in batches of 8 independent float4s to hide HBM latency.
__global__ __launch_bounds__(128)
void chunksum_kernel(const float* __restrict__ flat, const int* __restrict__ packed,
                     float* __restrict__ dw, int N) {
    __shared__ int ent[CHUNK + 1];
    const int t = threadIdx.x;
    const int base = blockIdx.x * CHUNK;
    const int cnt = min(CHUNK, N - base);
    if (t < cnt) ent[t] = packed[base + t];
    if (t == cnt) ent[t] = -1;            // sentinel: forces flush at end
    __syncthreads();

    f32x4 acc = {0.f, 0.f, 0.f, 0.f};
    for (int i0 = 0; i0 < cnt; i0 += 8) {
        const int m = min(8, cnt - i0);
        f32x4 v[8];
        #pragma unroll
        for (int j = 0; j < 8; ++j) {
            if (j < m) {
                int r = ent[i0 + j] & 0xFFFF;
                v[j] = *reinterpret_cast<const f32x4*>(&flat[(size_t)r * D_DIM + t * 4]);
            }
        }
        #pragma unroll
        for (int j = 0; j < 8; ++j) {
            if (j < m) {
                acc[0] += v[j][0]; acc[1] += v[j][1];
                acc[2] += v[j][2]; acc[3] += v[j][3];
                int k = ent[i0 + j] >> 16;
                if ((ent[i0 + j + 1] >> 16) != k) {   // uniform branch
                    float* p = &dw[(size_t)k * D_DIM + t * 4];
                    atomicAdd(p + 0, acc[0]);
                    atomicAdd(p + 1, acc[1]);
                    atomicAdd(p + 2, acc[2]);
                    atomicAdd(p + 3, acc[3]);
                    acc = f32x4{0.f, 0.f, 0.f, 0.f};
                }
            }
        }
    }
}

// ---------------------------------------------------------------------------
// EMA update + new embedding
__global__ __launch_bounds__(256)
void finalize_kernel(const float* __restrict__ ema_count, const float* __restrict__ ema_w,
                     const float* __restrict__ counts, const float* __restrict__ dw,
                     float* __restrict__ new_emb, float* __restrict__ new_count,
                     float* __restrict__ new_ema_w) {
    int gid = blockIdx.x * 256 + threadIdx.x;   // K*D/4 threads
    int k = gid >> 7;
    int d = (gid & 127) * 4;
    float nc = DECAY * ema_count[k] + OMD * counts[k];
    size_t off = (size_t)k * D_DIM + d;
    float4 w  = *reinterpret_cast<const float4*>(&ema_w[off]);
    float4 dv = *reinterpret_cast<const float4*>(&dw[off]);
    float4 nw;
    nw.x = DECAY * w.x + OMD * dv.x;
    nw.y = DECAY * w.y + OMD * dv.y;
    nw.z = DECAY * w.z + OMD * dv.z;
    nw.w = DECAY * w.w + OMD * dv.w;
    *reinterpret_cast<float4*>(&new_ema_w[off]) = nw;
    float inv = 1.0f / nc;
    float4 ne;
    ne.x = nw.x * inv; ne.y = nw.y * inv; ne.z = nw.z * inv; ne.w = nw.w * inv;
    *reinterpret_cast<float4*>(&new_emb[off]) = ne;
    if ((gid & 127) == 0) new_count[k] = nc;
}

// ---------------------------------------------------------------------------
__global__ __launch_bounds__(256)
void gather_kernel(const float* __restrict__ codebook, const float* __restrict__ new_emb,
                   const int* __restrict__ indices,
                   float* __restrict__ zq, float* __restrict__ zqb) {
    int gid = blockIdx.x * 256 + threadIdx.x;   // N*D/4 threads
    int r = gid >> 7;
    int d = (gid & 127) * 4;
    int k = indices[r];
    size_t src = (size_t)k * D_DIM + d;
    size_t dst = (size_t)r * D_DIM + d;
    *reinterpret_cast<float4*>(&zq[dst])  = *reinterpret_cast<const float4*>(&codebook[src]);
    *reinterpret_cast<float4*>(&zqb[dst]) = *reinterpret_cast<const float4*>(&new_emb[src]);
}

// ---------------------------------------------------------------------------
extern "C" void kernel_launch(void* const* d_in, const int* in_sizes, int n_in,
                              void* d_out, int out_size, void* d_ws, size_t ws_size,
                              hipStream_t stream) {
    const float* z_e_x     = (const float*)d_in[0];
    const float* codebook  = (const float*)d_in[1];
    const float* ema_count = (const float*)d_in[2];
    const float* ema_w     = (const float*)d_in[3];

    const int N = in_sizes[0] / D_DIM;   // 16384

    float* out = (float*)d_out;
    float* z_q_x     = out;
    float* z_q_x_bar = z_q_x + (size_t)N * D_DIM;
    float* new_emb   = z_q_x_bar + (size_t)N * D_DIM;
    float* new_count = new_emb + (size_t)K_CODES * D_DIM;
    float* new_ema_w = new_count + K_CODES;

    // workspace: indices | cbsqr | pval | pidx | counts | bh/bl(=dw) | offs | cursor | rowlist
    // dw (2 MB) aliases bh/bl (2 MB): bh/bl die after argmin, dw is written after.
    char* ws = (char*)d_ws;
    int*   indices = (int*)ws;                                   // N ints
    float* cbsqr   = (float*)(ws + (size_t)N * 4);               // K
    float* pval    = cbsqr + K_CODES;                            // N*NPART
    int*   pidx    = (int*)(pval + (size_t)N * NPART);           // N*NPART
    float* counts  = (float*)(pidx + (size_t)N * NPART);         // K
    _Float16* bh   = (_Float16*)(counts + K_CODES);              // K*D f16
    _Float16* bl   = bh + (size_t)K_CODES * D_DIM;               // K*D f16
    float* dw      = (float*)bh;                                 // K*D f32 (alias)
    int*   offs    = (int*)(bl + (size_t)K_CODES * D_DIM);       // K+1 ints
    int*   cursor  = offs + K_CODES + 1;                         // K ints
    int*   packed  = cursor + K_CODES;                           // N ints

    cbsqr_kernel<<<K_CODES, 64, 0, stream>>>(codebook, cbsqr, counts);
    splitB_kernel<<<(K_CODES * D_DIM / 4) / 256, 256, 0, stream>>>(codebook, bh, bl);

    dim3 g_argmin(N / BM, K_CODES / BN);   // (128, 8)
    argmin_mfma<<<g_argmin, 256, 0, stream>>>(z_e_x, bh, bl, cbsqr, pval, pidx);

    combine_kernel<<<(N + 255) / 256, 256, 0, stream>>>(pval, pidx, indices, counts, N);

    scan_kernel<<<1, 256, 0, stream>>>(counts, offs, cursor);
    scatter_kernel<<<(N + 255) / 256, 256, 0, stream>>>(indices, cursor, packed, N);

    // bh/bl dead -> zero the aliased dw region, then balanced segmented sum
    zero_kernel<<<(K_CODES * D_DIM / 4) / 256, 256, 0, stream>>>((float4*)dw, K_CODES * D_DIM / 4);
    chunksum_kernel<<<(N + CHUNK - 1) / CHUNK, 128, 0, stream>>>(z_e_x, packed, dw, N);

    finalize_kernel<<<(K_CODES * (D_DIM / 4)) / 256, 256, 0, stream>>>(
        ema_count, ema_w, counts, dw, new_emb, new_count, new_ema_w);

    gather_kernel<<<(N * (D_DIM / 4)) / 256, 256, 0, stream>>>(
        codebook, new_emb, indices, z_q_x, z_q_x_bar);
}